// Round 1
// baseline (229.708 us; speedup 1.0000x reference)
//
#include <hip/hip_runtime.h>

#define BB  4
#define CC  64
#define HH  128
#define WW  128
#define KS  21
#define PAD 10

// Each thread: 4 consecutive pixels (w0 = 4*(tid&31)), one di row, all 21 dj.
// Block: 256 threads = 8 rows (h-octet) x 32 pixel-quads. Grid: b * h8 * di.
__global__ __launch_bounds__(256) void corr_kernel(
    const float* __restrict__ feat1,
    const float* __restrict__ feat2,
    float* __restrict__ out)
{
    const int tid = threadIdx.x;
    int bi = blockIdx.x;
    const int di = bi % KS;  bi /= KS;
    const int h8 = bi % (HH / 8);
    const int b  = bi / (HH / 8);

    const int h  = h8 * 8 + (tid >> 5);      // row within octet
    const int w0 = (tid & 31) << 2;          // 4 consecutive pixels

    const int r = h + di - PAD;              // feat2 source row

    float acc[4][KS];
#pragma unroll
    for (int p = 0; p < 4; ++p)
#pragma unroll
        for (int d = 0; d < KS; ++d) acc[p][d] = 0.0f;

    if (r >= 0 && r < HH) {
        const float* f1p = feat1 + ((size_t)(b * CC) * HH + h) * WW + w0;
        const float* f2p = feat2 + ((size_t)(b * CC) * HH + r) * WW;

#pragma unroll 2
        for (int c = 0; c < CC; ++c) {
            const float4 a = *(const float4*)(f1p + (size_t)c * (HH * WW));

            // f2 window covering w0-12 .. w0+15 (28 floats, 7 aligned float4s).
            // Needed columns: w0-10 .. w0+13. Each float4 is entirely in or out
            // of [0, WW) because w0 % 4 == 0 and WW % 4 == 0.
            float win[28];
#pragma unroll
            for (int j = 0; j < 7; ++j) {
                const int off = w0 - 12 + 4 * j;
                float4 v = make_float4(0.f, 0.f, 0.f, 0.f);
                if (off >= 0 && off < WW)
                    v = *(const float4*)(f2p + (size_t)c * (HH * WW) + off);
                win[4 * j + 0] = v.x;
                win[4 * j + 1] = v.y;
                win[4 * j + 2] = v.z;
                win[4 * j + 3] = v.w;
            }

            // pixel w0+p, displacement dj -> f2 col w0+p+dj-10 -> win[p+dj+2]
#pragma unroll
            for (int d = 0; d < KS; ++d) {
                acc[0][d] += a.x * win[d + 2];
                acc[1][d] += a.y * win[d + 3];
                acc[2][d] += a.z * win[d + 4];
                acc[3][d] += a.w * win[d + 5];
            }
        }
    }

    const float scale = 1.0f / (float)CC;
    float* op = out + (((size_t)b * (KS * KS) + (size_t)di * KS) * HH + h) * WW + w0;
#pragma unroll
    for (int d = 0; d < KS; ++d) {
        float4 v = make_float4(acc[0][d] * scale, acc[1][d] * scale,
                               acc[2][d] * scale, acc[3][d] * scale);
        *(float4*)(op + (size_t)d * (HH * WW)) = v;
    }
}

extern "C" void kernel_launch(void* const* d_in, const int* in_sizes, int n_in,
                              void* d_out, int out_size, void* d_ws, size_t ws_size,
                              hipStream_t stream) {
    const float* feat1 = (const float*)d_in[0];
    const float* feat2 = (const float*)d_in[1];
    float* out = (float*)d_out;

    const int blocks = BB * (HH / 8) * KS;   // 4 * 16 * 21 = 1344
    corr_kernel<<<blocks, 256, 0, stream>>>(feat1, feat2, out);
}